// Round 1
// baseline (184.186 us; speedup 1.0000x reference)
//
#include <hip/hip_runtime.h>

typedef __attribute__((ext_vector_type(8))) __bf16 bf16x8;
typedef __attribute__((ext_vector_type(8))) ushort ushort8;
typedef __attribute__((ext_vector_type(4))) float floatx4;

union FragU { ushort8 u; bf16x8 b; };

// native RNE fp32->bf16 (v_cvt_pk_bf16_f32; compiler packs adjacent pairs)
__device__ inline ushort bfu(float a){
  __bf16 h = (__bf16)a;
  return __builtin_bit_cast(ushort, h);
}

#define BLOCKS 2048

// Fully register-resident pipeline: no LDS, no barriers, waves independent.
//   conv1 fp32 VALU -> F0/F1/F2 frags (k-order kw*32+ic), rows r = lm
//   conv2 OPERAND-SWAPPED: mfma(W2-as-A, F-as-B) -> C[m = oc2-low][n = row]
//     => lane (quad,lm) holds conv2 out for row=lm, oc2 = t*16 + quad*4 + rg.
//     With packed-col convention c = w*32 + 2*(oc2&15) + (oc2>>4), this lane's
//     16 values are exactly the linear A-frag k-range {h*32 + quad*8 + j}:
//     transpose is free (was: LDS round-trip + 2 barriers).
//   linear: mfma(h2-as-A, Wp-as-B), Wp N-permuted so lane lm owns out cols
//     4*lm..4*lm+3 -> float4 coalesced stores (unchanged from prev version).
__global__ __launch_bounds__(256) void cnn_fused(
    const float* __restrict__ x,  const float* __restrict__ W1,
    const float* __restrict__ b1, const float* __restrict__ W2,
    const float* __restrict__ b2, const float* __restrict__ Wp,
    const float* __restrict__ bp, float* __restrict__ out, int niter)
{
  const int tid  = threadIdx.x;
  const int wid  = tid >> 6;
  const int lane = tid & 63;
  const int lm   = lane & 15;
  const int quad = lane >> 4;

  // ---- loop-invariant register fragments ----
  // conv2 weights as A-frags: A[m=lm][k=quad*8+j] = W2[oc2=t*16+lm][ic=quad*8+j][kw=h]
  // (same data as the old B-frags: A/B lane mappings are symmetric for 16x16x32)
  FragU w2f[2][2];   // [oc2-tile][k-half]
  #pragma unroll
  for (int t = 0; t < 2; ++t)
    #pragma unroll
    for (int h = 0; h < 2; ++h)
      #pragma unroll
      for (int j = 0; j < 8; ++j)
        w2f[t][h].u[j] = bfu(W2[(t*16 + lm)*64 + (quad*8 + j)*2 + h]);

  // linear B-frags: out col o = 4*lm + t; k = c = h*32 + quad*8 + j;
  // c -> (w = h, oc2 = ((c&31)>>1) | ((c&1)<<4)); Wp flat = o*64 + oc2*2 + w
  FragU wpf[4][2];   // [t = o%4][k-half]
  #pragma unroll
  for (int t = 0; t < 4; ++t)
    #pragma unroll
    for (int h = 0; h < 2; ++h)
      #pragma unroll
      for (int j = 0; j < 8; ++j){
        const int cp  = quad*8 + j;
        const int oc2 = (cp >> 1) | ((cp & 1) << 4);
        wpf[t][h].u[j] = bfu(Wp[(4*lm + t)*64 + oc2*2 + h]);
      }

  // conv1 weights for ic = quad*8..quad*8+7 (this lane's F-frag k-range)
  float w1r[8][4], b1r[8];
  #pragma unroll
  for (int i = 0; i < 8; ++i){
    const int oc = quad*8 + i;
    w1r[i][0] = W1[oc*4+0]; w1r[i][1] = W1[oc*4+1];
    w1r[i][2] = W1[oc*4+2]; w1r[i][3] = W1[oc*4+3];
    b1r[i]    = b1[oc];
  }
  // conv2 bias for this lane's oc2 = t*16 + quad*4 + rg
  float b2lo[4], b2hi[4];
  #pragma unroll
  for (int rg = 0; rg < 4; ++rg){
    b2lo[rg] = b2[     quad*4 + rg];
    b2hi[rg] = b2[16 + quad*4 + rg];
  }
  const float4 bp4 = ((const float4*)bp)[lm];          // bp[4*lm .. 4*lm+3]

  // ---- per-wave contiguous row range ----
  const long gw   = (long)blockIdx.x * 4 + wid;
  long tilebase   = gw * ((long)niter * 16);

  const float4* x4 = (const float4*)x;
  float4 xa = x4[2*(tilebase + lm)];
  float4 xb = x4[2*(tilebase + lm) + 1];

  const floatx4 z = {0.f, 0.f, 0.f, 0.f};

  for (int it = 0; it < niter; ++it){
    // prefetch next tile's x
    float4 nxa, nxb;
    if (it + 1 < niter){
      const long nr = tilebase + 16 + lm;
      nxa = x4[2*nr]; nxb = x4[2*nr + 1];
    }

    // ---- conv1 (fp32): row lm, ic = quad*8+i, 3 windows ----
    FragU F0, F1, F2;
    #pragma unroll
    for (int i = 0; i < 8; ++i){
      const float w00 = w1r[i][0], w01 = w1r[i][1];
      const float w10 = w1r[i][2], w11 = w1r[i][3], bb = b1r[i];
      F0.u[i] = bfu(fmaxf(0.f, bb + w00*xa.x + w01*xa.y + w10*xb.x + w11*xb.y));
      F1.u[i] = bfu(fmaxf(0.f, bb + w00*xa.y + w01*xa.z + w10*xb.y + w11*xb.z));
      F2.u[i] = bfu(fmaxf(0.f, bb + w00*xa.z + w01*xa.w + w10*xb.z + w11*xb.w));
    }

    // ---- conv2 swapped: a[w][t], C[m = t*16+quad*4+rg][n = row lm] ----
    floatx4 a00 = z, a01 = z, a10 = z, a11 = z;
    a00 = __builtin_amdgcn_mfma_f32_16x16x32_bf16(w2f[0][0].b, F0.b, a00, 0,0,0);
    a00 = __builtin_amdgcn_mfma_f32_16x16x32_bf16(w2f[0][1].b, F1.b, a00, 0,0,0);
    a01 = __builtin_amdgcn_mfma_f32_16x16x32_bf16(w2f[1][0].b, F0.b, a01, 0,0,0);
    a01 = __builtin_amdgcn_mfma_f32_16x16x32_bf16(w2f[1][1].b, F1.b, a01, 0,0,0);
    a10 = __builtin_amdgcn_mfma_f32_16x16x32_bf16(w2f[0][0].b, F1.b, a10, 0,0,0);
    a10 = __builtin_amdgcn_mfma_f32_16x16x32_bf16(w2f[0][1].b, F2.b, a10, 0,0,0);
    a11 = __builtin_amdgcn_mfma_f32_16x16x32_bf16(w2f[1][0].b, F1.b, a11, 0,0,0);
    a11 = __builtin_amdgcn_mfma_f32_16x16x32_bf16(w2f[1][1].b, F2.b, a11, 0,0,0);

    // ---- bias+relu+cvt straight into linear A-frags (in-register "transpose") ----
    // ca_h.u[j]: j = 2*rg + s -> value a[w=h][t=s][rg], oc2 = s*16 + quad*4 + rg
    FragU ca0, ca1;
    #pragma unroll
    for (int rg = 0; rg < 4; ++rg){
      ca0.u[2*rg  ] = bfu(fmaxf(0.f, a00[rg] + b2lo[rg]));
      ca0.u[2*rg+1] = bfu(fmaxf(0.f, a01[rg] + b2hi[rg]));
      ca1.u[2*rg  ] = bfu(fmaxf(0.f, a10[rg] + b2lo[rg]));
      ca1.u[2*rg+1] = bfu(fmaxf(0.f, a11[rg] + b2hi[rg]));
    }

    // ---- linear: 4 N-tiles (t = o%4) ----
    floatx4 oacc[4];
    #pragma unroll
    for (int t = 0; t < 4; ++t){
      floatx4 acc = z;
      acc = __builtin_amdgcn_mfma_f32_16x16x32_bf16(ca0.b, wpf[t][0].b, acc, 0,0,0);
      acc = __builtin_amdgcn_mfma_f32_16x16x32_bf16(ca1.b, wpf[t][1].b, acc, 0,0,0);
      oacc[t] = acc;
    }

    // ---- coalesced float4 stores: lane lm owns cols 4*lm..4*lm+3 ----
    #pragma unroll
    for (int rg = 0; rg < 4; ++rg){
      float4 v;
      v.x = oacc[0][rg] + bp4.x;
      v.y = oacc[1][rg] + bp4.y;
      v.z = oacc[2][rg] + bp4.z;
      v.w = oacc[3][rg] + bp4.w;
      *(float4*)(out + (tilebase + quad*4 + rg)*64 + 4*lm) = v;
    }

    if (it + 1 < niter){ xa = nxa; xb = nxb; tilebase += 16; }
  }
}

extern "C" void kernel_launch(void* const* d_in, const int* in_sizes, int n_in,
                              void* d_out, int out_size, void* d_ws, size_t ws_size,
                              hipStream_t stream)
{
  const float* x  = (const float*)d_in[0];
  const float* W1 = (const float*)d_in[1];
  const float* b1 = (const float*)d_in[2];
  const float* W2 = (const float*)d_in[3];
  const float* b2 = (const float*)d_in[4];
  const float* Wp = (const float*)d_in[5];
  const float* bp = (const float*)d_in[6];
  float* out = (float*)d_out;

  const int rows  = in_sizes[0] / 8;            // B*S = 524288
  const int tiles = rows / 16;                  // 32768 wave-tiles
  const int niter = tiles / (BLOCKS * 4);       // 4
  cnn_fused<<<BLOCKS, 256, 0, stream>>>(x, W1, b1, W2, b2, Wp, bp, out, niter);
}